// Round 4
// baseline (317.954 us; speedup 1.0000x reference)
//
#include <hip/hip_runtime.h>
#include <hip/hip_bf16.h>

// Problem constants
// B=64, N=256, IN=512, OUT=512, K_SLOTS=8, DK=64
// inputs: node_feats (64*256*512 f32), adj (64*8*256*256 f32), weight (512*512 f32), bias (512 f32)
// out: (64*256*512) f32
//
// Split design (round 4): the fused 512x(512..1024)-thread shapes (rounds 0-3)
// all convoyed at 95-150us with every pipe idle.  Here: two LDS-free,
// barrier-free kernels with small blocks at high occupancy; all MFMA
// fragments are register-direct (per-lane contiguous global loads).
//   lin_kernel: hT[b][ks][d][m] = relu(X@W+bias)^T  (bf16 workspace, 16.8 MB)
//   agg_kernel: out[b][n][ks*64+d] = sum_m adj[b,ks,n,m] * hT[b,ks,d,m]

typedef __attribute__((ext_vector_type(8))) short short8;   // 8 bf16 (4 VGPRs) - MFMA A/B frag
typedef __attribute__((ext_vector_type(4))) float floatx4;  // MFMA C/D frag

__device__ __forceinline__ unsigned short f2bf(float f) {
    union { float f; unsigned u; } v; v.f = f;
    unsigned r = v.u + 0x7FFFu + ((v.u >> 16) & 1u);  // RNE
    return (unsigned short)(r >> 16);
}

// packed f32x2 -> bf16x2 (RNE); compiles to v_cvt_pk_bf16_f32 on gfx950
__device__ __forceinline__ unsigned pk2bf(float a, float b) {
    union { __hip_bfloat162 h; unsigned u; } cv;
    cv.h = __float22bfloat162_rn(make_float2(a, b));
    return cv.u;
}

// ---------------------------------------------------------------------------
// Pre-kernel: W (512x512, row-major [k][o]) -> Wt bf16 [o][k] (k contiguous)
// ---------------------------------------------------------------------------
__global__ __launch_bounds__(256) void wt_kernel(const float* __restrict__ W,
                                                 unsigned short* __restrict__ Wt) {
    __shared__ unsigned short t_lds[64 * 66];  // [o][k], pad 66 -> 2-way (free)
    const int tile = blockIdx.x;      // 0..63 (8x8 tiles)
    const int k0 = (tile >> 3) * 64;
    const int o0 = (tile & 7) * 64;
    const int t = threadIdx.x;
    const int c = t & 63;             // coalesced dim
    const int rb = t >> 6;            // 0..3
#pragma unroll
    for (int i = 0; i < 16; ++i) {
        int r = i * 4 + rb;           // k-row within tile
        t_lds[c * 66 + r] = f2bf(W[(size_t)(k0 + r) * 512 + o0 + c]);
    }
    __syncthreads();
#pragma unroll
    for (int i = 0; i < 16; ++i) {
        int o_r = i * 4 + rb;         // o-row within tile
        Wt[(size_t)(o0 + o_r) * 512 + k0 + c] = t_lds[o_r * 66 + c];
    }
}

// ---------------------------------------------------------------------------
// Chunked XCD swizzle for 2048 blocks on 8 XCDs: XCD x gets 256 consecutive
// work indices, so work-neighbors share that XCD's L2. (2048 % 8 == 0.)
// ---------------------------------------------------------------------------
__device__ __forceinline__ int xcd_chunk(int bid) {
    return (bid & 7) * 256 + (bid >> 3);
}

// ---------------------------------------------------------------------------
// lin_kernel: hT = relu(X @ Wslice + bias)^T, register-direct fragments.
// 2048 blocks = (b, mt4, ks); 256 threads = 4 waves; wave w: 16 m-rows x 64 d
// over k=512.  A <- X[b] rows (L2: 8 ks-siblings + 4 mt share X[b] on one
// XCD), B <- Wt slice (4 KB working set per kb step -> L1-hot).
// Work decode keeps the 8 ks-siblings of one (b,mt4) adjacent -> same XCD.
// ---------------------------------------------------------------------------
__global__ __launch_bounds__(256, 4) void lin_kernel(
    const float* __restrict__ X, const unsigned short* __restrict__ Wt,
    const float* __restrict__ bias, unsigned short* __restrict__ hT) {
    const int W_ = xcd_chunk(blockIdx.x);
    const int ks = W_ & 7;
    const int mt4 = (W_ >> 3) & 3;
    const int b = W_ >> 5;

    const int tid = threadIdx.x;
    const int lane = tid & 63, w = tid >> 6;     // wave 0..3
    const int lrow = lane & 15, quad = lane >> 4;

    const float* xp = X + (size_t)b * 131072
                        + (size_t)(mt4 * 64 + w * 16 + lrow) * 512 + quad * 8;
    const unsigned short* wp = Wt + (size_t)(ks * 64 + lrow) * 512 + quad * 8;

    floatx4 acc[4];
    const floatx4 fzero = {0.f, 0.f, 0.f, 0.f};
#pragma unroll
    for (int j = 0; j < 4; ++j) acc[j] = fzero;

#pragma unroll 2
    for (int kb = 0; kb < 16; ++kb) {
        const int k0 = kb * 32;
        float4 x0 = *(const float4*)(xp + k0);
        float4 x1 = *(const float4*)(xp + k0 + 4);
        short8 wf0 = *(const short8*)(wp + k0);            // d-tile 0
        short8 wf1 = *(const short8*)(wp + 8192 + k0);     // d-tile 1 (16*512)
        short8 wf2 = *(const short8*)(wp + 16384 + k0);    // d-tile 2
        short8 wf3 = *(const short8*)(wp + 24576 + k0);    // d-tile 3
        union { short8 s; unsigned u[4]; } af;
        af.u[0] = pk2bf(x0.x, x0.y);
        af.u[1] = pk2bf(x0.z, x0.w);
        af.u[2] = pk2bf(x1.x, x1.y);
        af.u[3] = pk2bf(x1.z, x1.w);
        acc[0] = __builtin_amdgcn_mfma_f32_16x16x32_bf16(af.s, wf0, acc[0], 0, 0, 0);
        acc[1] = __builtin_amdgcn_mfma_f32_16x16x32_bf16(af.s, wf1, acc[1], 0, 0, 0);
        acc[2] = __builtin_amdgcn_mfma_f32_16x16x32_bf16(af.s, wf2, acc[2], 0, 0, 0);
        acc[3] = __builtin_amdgcn_mfma_f32_16x16x32_bf16(af.s, wf3, acc[3], 0, 0, 0);
    }

    // epilogue: C/D col (lane&15) = d, rows (quad*4+reg) = m.  Write hT[d][m]:
    // per lane 4 consecutive m at fixed d -> one 8-B store; a wave-instr covers
    // 16 d-rows x 32 B (4 quads x 8 B) -> fine write-combining through L2.
    unsigned short* hslice = hT + ((size_t)(b * 8 + ks)) * 16384;
    const int mg = mt4 * 64 + w * 16 + quad * 4;
#pragma unroll
    for (int dt = 0; dt < 4; ++dt) {
        const int d = dt * 16 + lrow;
        const float bv = bias[ks * 64 + d];
        floatx4 c = acc[dt];
        uint2 pv;
        pv.x = pk2bf(fmaxf(c.x + bv, 0.f), fmaxf(c.y + bv, 0.f));
        pv.y = pk2bf(fmaxf(c.z + bv, 0.f), fmaxf(c.w + bv, 0.f));
        *(uint2*)(hslice + d * 256 + mg) = pv;
    }
}

// ---------------------------------------------------------------------------
// agg_kernel: out = adj @ h, register-direct fragments, no LDS, no barriers.
// 2048 blocks = (b, ks, nt); 256 threads = 4 waves; wave w: 16 n-rows x 64 d
// over m=256.  A <- adj (HBM stream, each 128-B line fetched exactly once,
// fully consumed), B <- hT slice (32 KB, L2-hot: 4 nt-siblings on one XCD).
// 16+ waves/CU each holding a full load batch in flight -> HBM saturation by
// TLP alone; nothing to convoy on.
// ---------------------------------------------------------------------------
__global__ __launch_bounds__(256, 4) void agg_kernel(
    const unsigned short* __restrict__ hT, const float* __restrict__ adj,
    float* __restrict__ out) {
    const int W_ = xcd_chunk(blockIdx.x);
    const int nt = W_ & 3;
    const int ks = (W_ >> 2) & 7;
    const int b = W_ >> 5;

    const int tid = threadIdx.x;
    const int lane = tid & 63, w = tid >> 6;     // wave 0..3
    const int lrow = lane & 15, quad = lane >> 4;

    const float* ap = adj + ((size_t)(b * 8 + ks)) * 65536
                          + (size_t)(nt * 64 + w * 16 + lrow) * 256 + quad * 8;
    const unsigned short* hp = hT + ((size_t)(b * 8 + ks)) * 16384
                                  + lrow * 256 + quad * 8;

    floatx4 acc[4];
    const floatx4 fzero = {0.f, 0.f, 0.f, 0.f};
#pragma unroll
    for (int j = 0; j < 4; ++j) acc[j] = fzero;

#pragma unroll 2
    for (int mt = 0; mt < 8; ++mt) {
        const int m0 = mt * 32;
        float4 a0 = *(const float4*)(ap + m0);
        float4 a1 = *(const float4*)(ap + m0 + 4);
        short8 h0 = *(const short8*)(hp + m0);             // d-tile 0
        short8 h1 = *(const short8*)(hp + 4096 + m0);      // d-tile 1 (16*256)
        short8 h2 = *(const short8*)(hp + 8192 + m0);      // d-tile 2
        short8 h3 = *(const short8*)(hp + 12288 + m0);     // d-tile 3
        union { short8 s; unsigned u[4]; } af;
        af.u[0] = pk2bf(a0.x, a0.y);
        af.u[1] = pk2bf(a0.z, a0.w);
        af.u[2] = pk2bf(a1.x, a1.y);
        af.u[3] = pk2bf(a1.z, a1.w);
        acc[0] = __builtin_amdgcn_mfma_f32_16x16x32_bf16(af.s, h0, acc[0], 0, 0, 0);
        acc[1] = __builtin_amdgcn_mfma_f32_16x16x32_bf16(af.s, h1, acc[1], 0, 0, 0);
        acc[2] = __builtin_amdgcn_mfma_f32_16x16x32_bf16(af.s, h2, acc[2], 0, 0, 0);
        acc[3] = __builtin_amdgcn_mfma_f32_16x16x32_bf16(af.s, h3, acc[3], 0, 0, 0);
    }

    // epilogue: C/D col (lane&15) = d, rows (quad*4+reg) = n.
    // Per (dt, reg): 16 lanes (lrow) write 16 consecutive floats = 64 B.
    const int n0 = nt * 64 + w * 16 + quad * 4;
    float* dst = out + ((size_t)b * 256 + n0) * 512 + ks * 64 + lrow;
#pragma unroll
    for (int dt = 0; dt < 4; ++dt) {
        float* p = dst + dt * 16;
        p[0 * 512] = acc[dt].x;
        p[1 * 512] = acc[dt].y;
        p[2 * 512] = acc[dt].z;
        p[3 * 512] = acc[dt].w;
    }
}

// ---------------------------------------------------------------------------
extern "C" void kernel_launch(void* const* d_in, const int* in_sizes, int n_in,
                              void* d_out, int out_size, void* d_ws, size_t ws_size,
                              hipStream_t stream) {
    const float* X    = (const float*)d_in[0];  // node_feats
    const float* adj  = (const float*)d_in[1];  // adj
    const float* W    = (const float*)d_in[2];  // weight
    const float* bias = (const float*)d_in[3];  // bias
    float* out = (float*)d_out;

    // workspace: Wt bf16 (512 KB) then hT bf16 [64][8][64][256] (16.8 MB)
    unsigned short* Wt = (unsigned short*)d_ws;
    unsigned short* hT = Wt + 512 * 512;

    wt_kernel<<<64, 256, 0, stream>>>(W, Wt);
    lin_kernel<<<2048, 256, 0, stream>>>(X, Wt, bias, hT);
    agg_kernel<<<2048, 256, 0, stream>>>(hT, adj, out);
}

// Round 5
// 258.572 us; speedup vs baseline: 1.2297x; 1.2297x over previous
//
#include <hip/hip_runtime.h>
#include <hip/hip_bf16.h>

// Problem constants
// B=64, N=256, IN=512, OUT=512, K_SLOTS=8, DK=64
// inputs: node_feats (64*256*512 f32), adj (64*8*256*256 f32), weight (512*512 f32), bias (512 f32)
// out: (64*256*512) f32
//
// Round-5 design. Lessons so far:
//  - register-direct MFMA fragment loads = stride-2KB 16-line gathers (rounds
//    1-4 all capped ~1.1 TB/s, VGPR 32, every pipe idle). LDS staging with
//    wave-contiguous loads (round 0) is the only pattern that moved data fast.
//  - round 0's stage-2 swizzle was non-bijective -> 4-way conflicts (7.2M);
//    pad-40 rows (80 B stride; bank-quad = 5*row+quad mod 8, 5 odd -> even
//    spread over 16 fragment rows) fix this without any XOR.
//  - 2 blocks/CU of lockstep barriers convoyed; here: small tiles, small
//    blocks, 5-7 blocks/CU, depth-2 register prefetch across each barrier.
// Split kernels:
//   lin_kernel: hT[b][ks][d][m] = relu(X@W+bias)^T (bf16 ws), 1024 blocks
//   agg_kernel: out[b,n,ks*64+d] = sum_m adj[b,ks,n,m]*hT[b,ks,d,m], 2048 blk

typedef __attribute__((ext_vector_type(8))) short short8;   // 8 bf16 (4 VGPRs)
typedef __attribute__((ext_vector_type(4))) float floatx4;  // MFMA C/D frag

__device__ __forceinline__ unsigned short f2bf(float f) {
    union { float f; unsigned u; } v; v.f = f;
    unsigned r = v.u + 0x7FFFu + ((v.u >> 16) & 1u);  // RNE
    return (unsigned short)(r >> 16);
}

// packed f32x2 -> bf16x2 (RNE); compiles to v_cvt_pk_bf16_f32 on gfx950
__device__ __forceinline__ unsigned pk2bf(float a, float b) {
    union { __hip_bfloat162 h; unsigned u; } cv;
    cv.h = __float22bfloat162_rn(make_float2(a, b));
    return cv.u;
}

// ---------------------------------------------------------------------------
// Pre-kernel: W (512x512, row-major [k][o]) -> Wt bf16 [o][k] (k contiguous)
// ---------------------------------------------------------------------------
__global__ __launch_bounds__(256) void wt_kernel(const float* __restrict__ W,
                                                 unsigned short* __restrict__ Wt) {
    __shared__ unsigned short t_lds[64 * 66];
    const int tile = blockIdx.x;      // 0..63 (8x8 tiles)
    const int k0 = (tile >> 3) * 64;
    const int o0 = (tile & 7) * 64;
    const int t = threadIdx.x;
    const int c = t & 63;
    const int rb = t >> 6;
#pragma unroll
    for (int i = 0; i < 16; ++i) {
        int r = i * 4 + rb;
        t_lds[c * 66 + r] = f2bf(W[(size_t)(k0 + r) * 512 + o0 + c]);
    }
    __syncthreads();
#pragma unroll
    for (int i = 0; i < 16; ++i) {
        int o_r = i * 4 + rb;
        Wt[(size_t)(o0 + o_r) * 512 + k0 + c] = t_lds[o_r * 66 + c];
    }
}

// ---------------------------------------------------------------------------
// lin_kernel: hT = relu(X @ Wslice + bias)^T.  1024 blocks = (b, ks, mh),
// 256 threads = 4 waves.  Block output: 64 d x 128 m over k=512 (16 steps).
// LDS: X-tile [128][40] bf16 dbuf + W-tile [64][40] dbuf = 30 KB -> 5 blk/CU.
// Staging: X loads are 8 rows x 128 B per wave-instr (8 full lines); W-chunk
// is a 16-B bf16 load from Wt (L2-hot).  Depth-2 reg prefetch across barriers.
// XCD chunking: consecutive work on one XCD keyed by b>>3 (matches agg).
// ---------------------------------------------------------------------------
__global__ __launch_bounds__(256, 4) void lin_kernel(
    const float* __restrict__ X, const unsigned short* __restrict__ Wt,
    const float* __restrict__ bias, unsigned short* __restrict__ hT) {
    __shared__ struct {
        unsigned short xt[2][128 * 40];  // pad-40 rows
        unsigned short wt[2][64 * 40];
    } lds;

    const int W_ = (blockIdx.x & 7) * 128 + (blockIdx.x >> 3);  // 1024 blocks
    const int mh = W_ & 1;
    const int ks = (W_ >> 1) & 7;
    const int b  = W_ >> 4;

    const int tid = threadIdx.x;
    const int lane = tid & 63, w = tid >> 6;     // wave 0..3
    const int lrow = lane & 15, quad = lane >> 4;

    // staging addresses: X in 4 passes of 32 rows; thread = 16 B of one row
    const float* xsrc = X + (size_t)b * 131072
                          + (size_t)(mh * 128 + (tid >> 3)) * 512 + (tid & 7) * 4;
    const unsigned short* wsrc = Wt + (size_t)(ks * 64 + (tid >> 2)) * 512 + (tid & 3) * 8;
    const int xw = (tid >> 3) * 40 + (tid & 7) * 4;   // + p*32*40
    const int ww = (tid >> 2) * 40 + (tid & 3) * 8;

    float bv[4];
#pragma unroll
    for (int j = 0; j < 4; ++j) bv[j] = bias[ks * 64 + 16 * j + lrow];

    floatx4 acc[2][4];
    const floatx4 fzero = {0.f, 0.f, 0.f, 0.f};
#pragma unroll
    for (int g = 0; g < 2; ++g)
#pragma unroll
        for (int j = 0; j < 4; ++j) acc[g][j] = fzero;

    float4 xa[4], xb[4];
    short8 wa, wb;

#define LLOAD(xr, wr, kb) do {                                          \
        xr[0] = *(const float4*)(xsrc + (kb) * 32);                     \
        xr[1] = *(const float4*)(xsrc + (kb) * 32 + 32 * 512);          \
        xr[2] = *(const float4*)(xsrc + (kb) * 32 + 64 * 512);          \
        xr[3] = *(const float4*)(xsrc + (kb) * 32 + 96 * 512);          \
        wr = *(const short8*)(wsrc + (kb) * 32);                        \
    } while (0)

#define LWRITE(buf, xr, wr) do {                                        \
        _Pragma("unroll")                                               \
        for (int p_ = 0; p_ < 4; ++p_) {                                \
            uint2 pv_;                                                  \
            pv_.x = pk2bf(xr[p_].x, xr[p_].y);                          \
            pv_.y = pk2bf(xr[p_].z, xr[p_].w);                          \
            *(uint2*)(lds.xt[buf] + p_ * 32 * 40 + xw) = pv_;           \
        }                                                               \
        *(short8*)(lds.wt[buf] + ww) = wr;                              \
    } while (0)

#define LCOMP(buf) do {                                                 \
        short8 af0 = *(const short8*)(lds.xt[buf] + (w * 32 + lrow) * 40 + quad * 8);      \
        short8 af1 = *(const short8*)(lds.xt[buf] + (w * 32 + 16 + lrow) * 40 + quad * 8); \
        _Pragma("unroll")                                               \
        for (int dt_ = 0; dt_ < 4; ++dt_) {                             \
            short8 wf = *(const short8*)(lds.wt[buf] + (dt_ * 16 + lrow) * 40 + quad * 8); \
            acc[0][dt_] = __builtin_amdgcn_mfma_f32_16x16x32_bf16(af0, wf, acc[0][dt_], 0, 0, 0); \
            acc[1][dt_] = __builtin_amdgcn_mfma_f32_16x16x32_bf16(af1, wf, acc[1][dt_], 0, 0, 0); \
        }                                                               \
    } while (0)

    LLOAD(xa, wa, 0);
    LLOAD(xb, wb, 1);
    LWRITE(0, xa, wa);
    LLOAD(xa, wa, 2);
    __syncthreads();

#pragma unroll
    for (int kb = 0; kb < 16; ++kb) {
        if (kb < 15) {
            if ((kb & 1) == 0) { LWRITE(1, xb, wb); if (kb < 13) LLOAD(xb, wb, kb + 3); }
            else               { LWRITE(0, xa, wa); if (kb < 13) LLOAD(xa, wa, kb + 3); }
        }
        LCOMP(kb & 1);
        if (kb < 15) __syncthreads();
    }
#undef LLOAD
#undef LWRITE
#undef LCOMP

    // epilogue: C row (quad*4+reg) = m, col (lane&15) = d -> hT[d][m], 8-B st
    unsigned short* hTsl = hT + (size_t)(b * 8 + ks) * 16384;
#pragma unroll
    for (int g = 0; g < 2; ++g) {
        const int m = mh * 128 + w * 32 + g * 16 + quad * 4;
#pragma unroll
        for (int dt = 0; dt < 4; ++dt) {
            const int d = dt * 16 + lrow;
            floatx4 c = acc[g][dt];
            uint2 pv;
            pv.x = pk2bf(fmaxf(c.x + bv[dt], 0.f), fmaxf(c.y + bv[dt], 0.f));
            pv.y = pk2bf(fmaxf(c.z + bv[dt], 0.f), fmaxf(c.w + bv[dt], 0.f));
            *(uint2*)(hTsl + d * 256 + m) = pv;
        }
    }
}

// ---------------------------------------------------------------------------
// agg_kernel: out = adj @ h.  2048 blocks = (b, ks, nt), 256 threads = 4
// waves.  Block output: 64 n x 64 d over m=256 (8 steps of m=32).
// LDS: adj-tile [64][40] bf16 dbuf + ht-tile [64][40] dbuf = 20 KB -> LDS
// allows 8 blk/CU (VGPR will cap ~6).  adj staging: 8 rows x 128 B per
// wave-instr = 8 full lines, each line fetched exactly once.  ht chunks are
// L2-hot (32 KB slice shared by 4 nt-siblings on one XCD).  Depth-2 prefetch.
// ---------------------------------------------------------------------------
__global__ __launch_bounds__(256, 4) void agg_kernel(
    const unsigned short* __restrict__ hT, const float* __restrict__ adj,
    float* __restrict__ out) {
    __shared__ struct {
        unsigned short at[2][64 * 40];   // adj tile, pad-40
        unsigned short ht[2][64 * 40];   // hT chunk, pad-40
    } lds;

    const int W_ = (blockIdx.x & 7) * 256 + (blockIdx.x >> 3);  // 2048 blocks
    const int nt = W_ & 3;
    const int ks = (W_ >> 2) & 7;
    const int b  = W_ >> 5;

    const int tid = threadIdx.x;
    const int lane = tid & 63, w = tid >> 6;     // wave 0..3
    const int lrow = lane & 15, quad = lane >> 4;

    // staging: adj in 2 passes of 32 rows (thread = 16 B of one row);
    // ht chunk: thread = 16 B of one d-row
    const float* asrc = adj + (size_t)(b * 8 + ks) * 65536
                            + (size_t)(nt * 64 + (tid >> 3)) * 256 + (tid & 7) * 4;
    const unsigned short* hsrc = hT + (size_t)(b * 8 + ks) * 16384
                                    + (tid >> 2) * 256 + (tid & 3) * 8;
    const int aw = (tid >> 3) * 40 + (tid & 7) * 4;   // + p*32*40
    const int hw = (tid >> 2) * 40 + (tid & 3) * 8;

    floatx4 acc[4];
    const floatx4 fzero = {0.f, 0.f, 0.f, 0.f};
#pragma unroll
    for (int j = 0; j < 4; ++j) acc[j] = fzero;

    float4 a0a, a1a, a0b, a1b;
    short8 ha, hb;

#define ALOAD(r0, r1, hr, mt) do {                                      \
        r0 = *(const float4*)(asrc + (mt) * 32);                        \
        r1 = *(const float4*)(asrc + (mt) * 32 + 32 * 256);             \
        hr = *(const short8*)(hsrc + (mt) * 32);                        \
    } while (0)

#define AWRITE(buf, r0, r1, hr) do {                                    \
        uint2 p0_; p0_.x = pk2bf(r0.x, r0.y); p0_.y = pk2bf(r0.z, r0.w); \
        *(uint2*)(lds.at[buf] + aw) = p0_;                              \
        uint2 p1_; p1_.x = pk2bf(r1.x, r1.y); p1_.y = pk2bf(r1.z, r1.w); \
        *(uint2*)(lds.at[buf] + 32 * 40 + aw) = p1_;                    \
        *(short8*)(lds.ht[buf] + hw) = hr;                              \
    } while (0)

#define ACOMP(buf) do {                                                 \
        short8 af = *(const short8*)(lds.at[buf] + (w * 16 + lrow) * 40 + quad * 8); \
        _Pragma("unroll")                                               \
        for (int dt_ = 0; dt_ < 4; ++dt_) {                             \
            short8 hf = *(const short8*)(lds.ht[buf] + (dt_ * 16 + lrow) * 40 + quad * 8); \
            acc[dt_] = __builtin_amdgcn_mfma_f32_16x16x32_bf16(af, hf, acc[dt_], 0, 0, 0); \
        }                                                               \
    } while (0)

    ALOAD(a0a, a1a, ha, 0);
    ALOAD(a0b, a1b, hb, 1);
    AWRITE(0, a0a, a1a, ha);
    ALOAD(a0a, a1a, ha, 2);
    __syncthreads();

#pragma unroll
    for (int mt = 0; mt < 8; ++mt) {
        if (mt < 7) {
            if ((mt & 1) == 0) { AWRITE(1, a0b, a1b, hb); if (mt < 5) ALOAD(a0b, a1b, hb, mt + 3); }
            else               { AWRITE(0, a0a, a1a, ha); if (mt < 5) ALOAD(a0a, a1a, ha, mt + 3); }
        }
        ACOMP(mt & 1);
        if (mt < 7) __syncthreads();
    }
#undef ALOAD
#undef AWRITE
#undef ACOMP

    // epilogue: C row (quad*4+reg) = n, col (lane&15) = d
    const int n0 = nt * 64 + w * 16 + quad * 4;
    float* dst = out + ((size_t)b * 256 + n0) * 512 + ks * 64 + lrow;
#pragma unroll
    for (int dt = 0; dt < 4; ++dt) {
        float* p = dst + dt * 16;
        p[0 * 512] = acc[dt].x;
        p[1 * 512] = acc[dt].y;
        p[2 * 512] = acc[dt].z;
        p[3 * 512] = acc[dt].w;
    }
}

// ---------------------------------------------------------------------------
extern "C" void kernel_launch(void* const* d_in, const int* in_sizes, int n_in,
                              void* d_out, int out_size, void* d_ws, size_t ws_size,
                              hipStream_t stream) {
    const float* X    = (const float*)d_in[0];  // node_feats
    const float* adj  = (const float*)d_in[1];  // adj
    const float* W    = (const float*)d_in[2];  // weight
    const float* bias = (const float*)d_in[3];  // bias
    float* out = (float*)d_out;

    // workspace: Wt bf16 (512 KB) then hT bf16 [64][8][64][256] (16.8 MB)
    unsigned short* Wt = (unsigned short*)d_ws;
    unsigned short* hT = Wt + 512 * 512;

    wt_kernel<<<64, 256, 0, stream>>>(W, Wt);
    lin_kernel<<<1024, 256, 0, stream>>>(X, Wt, bias, hT);
    agg_kernel<<<2048, 256, 0, stream>>>(hT, adj, out);
}